// Round 5
// baseline (454.868 us; speedup 1.0000x reference)
//
#include <hip/hip_runtime.h>
#include <math.h>

typedef __bf16 bf16;
typedef __bf16 bf16x8 __attribute__((ext_vector_type(8)));
typedef __bf16 bf16x4 __attribute__((ext_vector_type(4)));
typedef float  f32x4  __attribute__((ext_vector_type(4)));

namespace {
constexpr int B_ = 2, S_ = 2048, HID_ = 1024, H_ = 16, D_ = 64, R_ = 128, NREL_ = 257;
constexpr float LOG2E_ = 1.44269504f;
constexpr float QSC_ = 0.125f * LOG2E_;   // 1/sqrt(D) and log2(e), folded into Q
}

static __device__ __forceinline__ f32x4 mfma16(bf16x8 a, bf16x8 b, f32x4 c) {
  return __builtin_amdgcn_mfma_f32_16x16x32_bf16(a, b, c, 0, 0, 0);
}
static __device__ __forceinline__ void split2(float f, bf16 &hi, bf16 &lo) {
  hi = (bf16)f; lo = (bf16)(f - (float)hi);
}

// ---------------- prep: scaled mask, rkE*8 -> bf16 [272][64], rvE^T -> bf16 [64][288]
__global__ void prep_kernel(const float* __restrict__ st_mask,
                            const float* __restrict__ rkE, const float* __restrict__ rvE,
                            float* __restrict__ msk2, bf16* __restrict__ rkEb,
                            bf16* __restrict__ rvTb)
{
  const int t0 = blockIdx.x * 256 + threadIdx.x;
  const int NT = gridDim.x * 256;
  for (int t = t0; t < B_ * S_; t += NT)
    msk2[t] = (1.f - st_mask[t]) * -10000.f * LOG2E_;
  for (int t = t0; t < 272 * 64; t += NT) {
    const int bk = t >> 6, d = t & 63;
    rkEb[t] = (bk < NREL_) ? (bf16)(rkE[bk * D_ + d] * 8.0f) : (bf16)0.f;
  }
  for (int t = t0; t < 64 * 288; t += NT) {
    const int d = t / 288, c = t - d * 288;
    rvTb[t] = (c < NREL_) ? (bf16)rvE[c * D_ + d] : (bf16)0.f;
  }
}

// ---------------- merged QKV projection, split-bf16 MFMA, 128x64 tile.
__global__ __launch_bounds__(256, 3) void qkv_mfma_kernel(
    const float* __restrict__ A,
    const float* __restrict__ Wq, const float* __restrict__ bq,
    const float* __restrict__ Wk, const float* __restrict__ bk,
    const float* __restrict__ Wv, const float* __restrict__ bv,
    bf16* __restrict__ Qh, bf16* __restrict__ Ql,
    bf16* __restrict__ Kb, bf16* __restrict__ Vt)
{
  const int n0 = blockIdx.x * 64;
  const int m0 = blockIdx.y * 128;
  const int tid = threadIdx.x;
  const int l = tid & 63, w = tid >> 6;
  const int cl = l & 15, g = l >> 4, kg8 = g * 8;

  __shared__ __align__(16) bf16 Ah[128][40], Al[128][40];
  __shared__ __align__(16) bf16 Bh[3][64][40], Bl[3][64][40];

  f32x4 acc[2][3][4];
#pragma unroll
  for (int hf = 0; hf < 2; ++hf)
#pragma unroll
    for (int s = 0; s < 3; ++s)
#pragma unroll
      for (int nf = 0; nf < 4; ++nf)
#pragma unroll
        for (int i = 0; i < 4; ++i) acc[hf][s][nf][i] = 0.f;

  const int srow = tid >> 2, sk = (tid & 3) * 8;
  const float* Ws_[3] = {Wq, Wk, Wv};

  for (int kt = 0; kt < HID_ / 32; ++kt) {
#pragma unroll
    for (int hf = 0; hf < 2; ++hf) {
      const float* ap = A + (size_t)(m0 + hf * 64 + srow) * HID_ + kt * 32 + sk;
      const float4 a0 = *(const float4*)ap, a1 = *(const float4*)(ap + 4);
      const float av[8] = {a0.x,a0.y,a0.z,a0.w,a1.x,a1.y,a1.z,a1.w};
      bf16x8 hi, lo;
#pragma unroll
      for (int i = 0; i < 8; ++i) { bf16 h, o; split2(av[i], h, o); hi[i] = h; lo[i] = o; }
      *(bf16x8*)&Ah[hf * 64 + srow][sk] = hi;
      *(bf16x8*)&Al[hf * 64 + srow][sk] = lo;
    }
#pragma unroll
    for (int s = 0; s < 3; ++s) {
      const float* wp = Ws_[s] + (size_t)(n0 + srow) * HID_ + kt * 32 + sk;
      const float4 w0 = *(const float4*)wp, w1 = *(const float4*)(wp + 4);
      const float wv[8] = {w0.x,w0.y,w0.z,w0.w,w1.x,w1.y,w1.z,w1.w};
      bf16x8 hi, lo;
#pragma unroll
      for (int i = 0; i < 8; ++i) { bf16 h, o; split2(wv[i], h, o); hi[i] = h; lo[i] = o; }
      *(bf16x8*)&Bh[s][srow][sk] = hi;
      *(bf16x8*)&Bl[s][srow][sk] = lo;
    }
    __syncthreads();
    bf16x8 fah[2], fal[2];
#pragma unroll
    for (int hf = 0; hf < 2; ++hf) {
      fah[hf] = *(const bf16x8*)&Ah[hf * 64 + w * 16 + cl][kg8];
      fal[hf] = *(const bf16x8*)&Al[hf * 64 + w * 16 + cl][kg8];
    }
#pragma unroll
    for (int s = 0; s < 3; ++s)
#pragma unroll
      for (int nf = 0; nf < 4; ++nf) {
        const bf16x8 fbh = *(const bf16x8*)&Bh[s][nf * 16 + cl][kg8];
        const bf16x8 fbl = *(const bf16x8*)&Bl[s][nf * 16 + cl][kg8];
#pragma unroll
        for (int hf = 0; hf < 2; ++hf) {
          acc[hf][s][nf] = mfma16(fah[hf], fbh, acc[hf][s][nf]);
          acc[hf][s][nf] = mfma16(fah[hf], fbl, acc[hf][s][nf]);
          acc[hf][s][nf] = mfma16(fal[hf], fbh, acc[hf][s][nf]);
        }
      }
    __syncthreads();
  }

  const float* bs_[3] = {bq, bk, bv};
#pragma unroll
  for (int s = 0; s < 3; ++s)
#pragma unroll
    for (int nf = 0; nf < 4; ++nf) {
      const int n = n0 + nf * 16 + cl;
      const float bias = bs_[s][n];
      const int hd = n >> 6, d = n & 63;
#pragma unroll
      for (int hf = 0; hf < 2; ++hf)
#pragma unroll
        for (int reg = 0; reg < 4; ++reg) {
          const int m = m0 + hf * 64 + w * 16 + g * 4 + reg;
          const int b = m >> 11, sq = m & (S_ - 1);
          const float val = acc[hf][s][nf][reg] + bias;
          if (s == 0) {
            bf16 h, o; split2(val * QSC_, h, o);
            const size_t idx = ((size_t)(b * H_ + hd) * S_ + sq) * D_ + d;
            Qh[idx] = h; Ql[idx] = o;
          } else if (s == 1) {
            Kb[((size_t)(b * H_ + hd) * S_ + sq) * D_ + d] = (bf16)val;
          } else {
            Vt[((size_t)(b * H_ + hd) * D_ + d) * S_ + sq] = (bf16)val;
          }
        }
    }
}

// ---------------- attention: QB=32, 4 waves, NO LDS K/V staging, no loop barriers.
// wave w: q-slice wq=(w&1)*16, j-half wh=w>>1. Lane: q=wq+cl fixed, j per (nf,reg).
// T[32][296] doubles as rel-key-score table then rel-prob table (unique-owner cells).
__global__ __launch_bounds__(256, 4) void attn_kernel(
    const bf16* __restrict__ Qh, const bf16* __restrict__ Ql,
    const bf16* __restrict__ Kb, const bf16* __restrict__ Vt,
    const float* __restrict__ msk2, const bf16* __restrict__ rkEb,
    const bf16* __restrict__ rvTb, float* __restrict__ out)
{
  const int qt = blockIdx.x, h = blockIdx.y, b = blockIdx.z;
  const int q0 = qt * 32;
  const int tid = threadIdx.x;
  const int l = tid & 63, w = tid >> 6;
  const int wq = (w & 1) * 16, wh = w >> 1;
  const int cl = l & 15, g = l >> 4, kg8 = g * 8;
  const int lq = wq + cl;

  __shared__ __align__(16) bf16 T[32][296];
  __shared__ __align__(16) bf16 ph[32][72];
  __shared__ float ctxred[2][32][36];
  __shared__ float red[2][3][32];
  __shared__ float lsum_s[32];

  const size_t bh  = (size_t)(b * H_ + h) * S_;
  const size_t bhd = (size_t)(b * H_ + h) * D_;

  // Q fragments (pre-scaled by log2e/8)
  bf16x8 qh0, qh1, ql0, ql1;
  {
    const size_t base = (bh + q0 + lq) * D_ + kg8;
    qh0 = *(const bf16x8*)(Qh + base);
    qh1 = *(const bf16x8*)(Qh + base + 32);
    ql0 = *(const bf16x8*)(Ql + base);
    ql1 = *(const bf16x8*)(Ql + base + 32);
  }

  // rel key scores into T (rkEb already *8; log2e arrives via Q)
  {
    const int nt0 = wh ? 9 : 0, ntE = wh ? 17 : 9;
    for (int nt = nt0; nt < ntE; ++nt) {
      f32x4 r; r[0] = r[1] = r[2] = r[3] = 0.f;
      const bf16x8 a0 = *(const bf16x8*)(rkEb + (size_t)(nt * 16 + cl) * 64 + kg8);
      const bf16x8 a1 = *(const bf16x8*)(rkEb + (size_t)(nt * 16 + cl) * 64 + 32 + kg8);
      r = mfma16(a0, qh0, r); r = mfma16(a0, ql0, r);
      r = mfma16(a1, qh1, r); r = mfma16(a1, ql1, r);
      bf16x4 pk;
#pragma unroll
      for (int reg = 0; reg < 4; ++reg) pk[reg] = (bf16)r[reg];
      *(bf16x4*)&T[lq][nt * 16 + g * 4] = pk;
    }
  }
  __syncthreads();
  const float rs_lo = (float)T[lq][0];
  const float rs_hi = (float)T[lq][2 * R_];
  const int qg = q0 + lq;

  f32x4 ctx[4];
#pragma unroll
  for (int nf = 0; nf < 4; ++nf) { ctx[nf][0]=0.f; ctx[nf][1]=0.f; ctx[nf][2]=0.f; ctx[nf][3]=0.f; }
  float lsum = 0.f, plo = 0.f, phi = 0.f;

  const bf16* Kbase = Kb + bh * D_;
  const bf16* Vbase = Vt + bhd * S_;
  const float* mbase = msk2 + b * S_;

  for (int kt = 0; kt < S_ / 64; ++kt) {
    const int j0 = kt * 64 + wh * 32;
    const bf16* kp = Kbase + (size_t)j0 * D_;
    const bf16x8 a00 = *(const bf16x8*)(kp + cl * 64 + kg8);
    const bf16x8 a01 = *(const bf16x8*)(kp + cl * 64 + 32 + kg8);
    const bf16x8 a10 = *(const bf16x8*)(kp + (16 + cl) * 64 + kg8);
    const bf16x8 a11 = *(const bf16x8*)(kp + (16 + cl) * 64 + 32 + kg8);

    f32x4 s0, s1;
    s0[0]=s0[1]=s0[2]=s0[3]=0.f; s1[0]=s1[1]=s1[2]=s1[3]=0.f;
    s0 = mfma16(a00, qh0, s0); s0 = mfma16(a00, ql0, s0);
    s0 = mfma16(a01, qh1, s0); s0 = mfma16(a01, ql1, s0);
    s1 = mfma16(a10, qh0, s1); s1 = mfma16(a10, ql0, s1);
    s1 = mfma16(a11, qh1, s1); s1 = mfma16(a11, ql1, s1);

    const float4 mk0 = *(const float4*)(mbase + j0 + g * 4);
    const float4 mk1 = *(const float4*)(mbase + j0 + 16 + g * 4);
    const int dlt = kt * 64 - q0;
    const int mode = (dlt <= -192) ? 0 : (dlt >= 192 ? 1 : 2);

#pragma unroll
    for (int nf = 0; nf < 2; ++nf) {
      const f32x4 sa = nf ? s1 : s0;
      const float4 mkv = nf ? mk1 : mk0;
      const float mks[4] = {mkv.x, mkv.y, mkv.z, mkv.w};
      float p[4];
      if (mode == 0) {
#pragma unroll
        for (int reg = 0; reg < 4; ++reg) p[reg] = exp2f(sa[reg] + rs_lo + mks[reg]);
        plo += (p[0] + p[1]) + (p[2] + p[3]);
      } else if (mode == 1) {
#pragma unroll
        for (int reg = 0; reg < 4; ++reg) p[reg] = exp2f(sa[reg] + rs_hi + mks[reg]);
        phi += (p[0] + p[1]) + (p[2] + p[3]);
      } else {
        const int jb = j0 + nf * 16 + g * 4;
#pragma unroll
        for (int reg = 0; reg < 4; ++reg) {
          const int bkv = jb + reg - qg + R_;
          const int bkc = bkv < 0 ? 0 : (bkv > 2 * R_ ? 2 * R_ : bkv);
          const float pv = exp2f(sa[reg] + (float)T[lq][bkc] + mks[reg]);
          p[reg] = pv;
          if (bkv <= 0)           plo += pv;
          else if (bkv >= 2 * R_) phi += pv;
          else                    T[lq][bkv] = (bf16)pv;   // unique owner cell
        }
      }
      lsum += (p[0] + p[1]) + (p[2] + p[3]);
      bf16x4 pk;
#pragma unroll
      for (int reg = 0; reg < 4; ++reg) pk[reg] = (bf16)p[reg];
      *(bf16x4*)&ph[lq][wh * 32 + nf * 16 + g * 4] = pk;
    }

    // PV over own j-half (intra-wave LDS round trip, lgkmcnt-ordered)
    const bf16x8 pa = *(const bf16x8*)&ph[lq][wh * 32 + kg8];
#pragma unroll
    for (int nf = 0; nf < 4; ++nf) {
      const bf16x8 vb = *(const bf16x8*)(Vbase + (size_t)(nf * 16 + cl) * S_ + j0 + kg8);
      ctx[nf] = mfma16(pa, vb, ctx[nf]);
    }
  }

  // lane-group reductions (q = lq fixed per lane)
  lsum += __shfl_xor(lsum, 16); lsum += __shfl_xor(lsum, 32);
  plo  += __shfl_xor(plo, 16);  plo  += __shfl_xor(plo, 32);
  phi  += __shfl_xor(phi, 16);  phi  += __shfl_xor(phi, 32);
  if (l < 16) {
    red[wh][0][wq + l] = lsum;
    red[wh][1][wq + l] = plo;
    red[wh][2][wq + l] = phi;
  }
  __syncthreads();   // all T interior writes + red complete

  // give away non-assigned ctx halves: wh=0 keeps nf{0,1}, wh=1 keeps nf{2,3}
  {
    const int nfs = wh ? 0 : 2;
#pragma unroll
    for (int k2 = 0; k2 < 2; ++k2)
#pragma unroll
      for (int reg = 0; reg < 4; ++reg)
        ctxred[wh][wq + g * 4 + reg][k2 * 16 + cl] = ctx[nfs + k2][reg];
  }
  if (tid < 32) {
    lsum_s[tid]    = red[0][0][tid] + red[1][0][tid];
    T[tid][0]      = (bf16)(red[0][1][tid] + red[1][1][tid]);
    T[tid][2 * R_] = (bf16)(red[0][2][tid] + red[1][2][tid]);
  }
  // zero pad columns 257..287
  for (int t = tid; t < 32 * 32; t += 256) {
    const int c = t & 31;
    if (c) T[t >> 5][256 + c] = (bf16)0.f;
  }
  // zero interior cells whose j is out of range (edge q-tiles only)
  if (q0 < R_ || q0 > S_ - R_ - 32) {
    for (int t = tid; t < 32 * 256; t += 256) {
      const int r = t >> 8, c = t & 255;
      if (c >= 1) {
        const int j = q0 + r + c - R_;
        if (j < 0 || j >= S_) T[r][c] = (bf16)0.f;
      }
    }
  }
  __syncthreads();

  // complete assigned ctx halves
  const int nfa = wh ? 2 : 0;
#pragma unroll
  for (int k2 = 0; k2 < 2; ++k2)
#pragma unroll
    for (int reg = 0; reg < 4; ++reg)
      ctx[nfa + k2][reg] += ctxred[wh ^ 1][wq + g * 4 + reg][k2 * 16 + cl];

  // rel-value GEMM: ctx += T(relp)[32][288] @ rvE (bf16, rvTb transposed)
#pragma unroll
  for (int ks = 0; ks < 9; ++ks) {
    const bf16x8 pa = *(const bf16x8*)&T[lq][ks * 32 + kg8];
#pragma unroll
    for (int k2 = 0; k2 < 2; ++k2) {
      const int nf = nfa + k2;
      const bf16x8 vb = *(const bf16x8*)(rvTb + (size_t)(nf * 16 + cl) * 288 + ks * 32 + kg8);
      ctx[nf] = mfma16(pa, vb, ctx[nf]);
    }
  }

  // normalize + store
#pragma unroll
  for (int k2 = 0; k2 < 2; ++k2) {
    const int nf = nfa + k2;
#pragma unroll
    for (int reg = 0; reg < 4; ++reg) {
      const int qrow = wq + g * 4 + reg;
      const float invl = 1.f / lsum_s[qrow];
      out[(size_t)(b * S_ + q0 + qrow) * HID_ + h * 64 + nf * 16 + cl] = ctx[nf][reg] * invl;
    }
  }
}

extern "C" void kernel_launch(void* const* d_in, const int* in_sizes, int n_in,
                              void* d_out, int out_size, void* d_ws, size_t ws_size,
                              hipStream_t stream)
{
  (void)in_sizes; (void)n_in; (void)out_size; (void)ws_size;
  const float* hidden  = (const float*)d_in[0];
  const float* st_mask = (const float*)d_in[1];
  const float* Wq = (const float*)d_in[2];
  const float* bq = (const float*)d_in[3];
  const float* Wk = (const float*)d_in[4];
  const float* bk = (const float*)d_in[5];
  const float* Wv = (const float*)d_in[6];
  const float* bv = (const float*)d_in[7];
  const float* rkE = (const float*)d_in[8];
  const float* rvE = (const float*)d_in[9];
  float* out = (float*)d_out;

  const size_t per = (size_t)B_ * H_ * S_ * D_;   // 4,194,304 elements
  bf16* Qh   = (bf16*)d_ws;
  bf16* Ql   = Qh + per;
  bf16* Kb   = Ql + per;
  bf16* Vt   = Kb + per;
  bf16* rkEb = Vt + per;                 // 272*64
  bf16* rvTb = rkEb + 272 * 64;          // 64*288
  float* msk2 = (float*)(Qh + 4 * per + 36864);

  prep_kernel<<<dim3(40), 256, 0, stream>>>(st_mask, rkE, rvE, msk2, rkEb, rvTb);
  qkv_mfma_kernel<<<dim3(HID_ / 64, B_ * S_ / 128), 256, 0, stream>>>(
      hidden, Wq, bq, Wk, bk, Wv, bv, Qh, Ql, Kb, Vt);
  attn_kernel<<<dim3(S_ / 32, H_, B_), 256, 0, stream>>>(
      Qh, Ql, Kb, Vt, msk2, rkEb, rvTb, out);
}